// Round 6
// baseline (240.562 us; speedup 1.0000x reference)
//
#include <hip/hip_runtime.h>

typedef int v4i __attribute__((ext_vector_type(4)));

#define THREADS 1024
#define EPT 16                         // edges per thread per chunk
#define CHUNK (THREADS * EPT)          // 16384 edges
#define NBLK 256                       // persistent: 1 block per CU
#define PART_BITS 18
#define PART_NODES (1 << PART_BITS)    // 262144 nodes / partition
#define PART_WORDS (PART_NODES / 16)   // 16384 words = 64 KB
#define NPART 4
#define TBL 450                        // NUM_RELS * 9

// Raw barrier that does NOT drain vmcnt (keeps register prefetch in flight).
// LDS ordering via explicit lgkmcnt(0); sched_barrier pins (rule #18).
#define BAR() do {                                            \
    asm volatile("s_waitcnt lgkmcnt(0)" ::: "memory");        \
    __builtin_amdgcn_s_barrier();                             \
    __builtin_amdgcn_sched_barrier(0);                        \
} while (0)

__global__ void zero_kernel(float* __restrict__ out, int n) {
    int i = blockIdx.x * blockDim.x + threadIdx.x;
    if (i < n) out[i] = 0.0f;
}

// Pack node_type (0..2) into 2 bits/node: 16 nodes per uint32 (256 KB total).
__global__ void pack_nt_kernel(const int* __restrict__ nt,
                               unsigned int* __restrict__ packed,
                               int nwords, int N) {
    int i = blockIdx.x * blockDim.x + threadIdx.x;
    if (i >= nwords) return;
    unsigned int word = 0;
    int base = i * 16;
    if (base + 16 <= N) {
        #pragma unroll
        for (int j = 0; j < 4; ++j) {
            int4 v = *reinterpret_cast<const int4*>(nt + base + j * 4);
            word |= (unsigned)(v.x & 3) << (2 * (j * 4 + 0));
            word |= (unsigned)(v.y & 3) << (2 * (j * 4 + 1));
            word |= (unsigned)(v.z & 3) << (2 * (j * 4 + 2));
            word |= (unsigned)(v.w & 3) << (2 * (j * 4 + 3));
        }
    } else {
        for (int j = 0; base + j < N; ++j)
            word |= (unsigned)(nt[base + j] & 3) << (2 * j);
    }
    packed[i] = word;
}

// Lane-contiguous chunk stream: wave w covers [cb .. cb+1024), lane offset
// j*256 + lane*4 -> 4 lanes share each 64B line (coalesced).
__device__ __forceinline__ void prefetch_chunk(
        const int* __restrict__ et_g, const int* __restrict__ es_g,
        const int* __restrict__ ed_g, const int* __restrict__ eb_g,
        long cb, int (&ET)[EPT], int (&SV)[EPT], int (&DV)[EPT], int (&EB)[EPT]) {
    #pragma unroll
    for (int j = 0; j < EPT / 4; ++j) {
        long idx = cb + (long)j * 256;
        v4i a = __builtin_nontemporal_load(reinterpret_cast<const v4i*>(et_g + idx));
        v4i b = __builtin_nontemporal_load(reinterpret_cast<const v4i*>(es_g + idx));
        v4i c = __builtin_nontemporal_load(reinterpret_cast<const v4i*>(ed_g + idx));
        v4i d = __builtin_nontemporal_load(reinterpret_cast<const v4i*>(eb_g + idx));
        #pragma unroll
        for (int q = 0; q < 4; ++q) {
            ET[j * 4 + q] = a[q]; SV[j * 4 + q] = b[q];
            DV[j * 4 + q] = c[q]; EB[j * 4 + q] = d[q];
        }
    }
}

// One chunk: 4x {fill 64KB partition -> bar -> LDS gather} with next-chunk
// register prefetch issued after the first fill's barrier (hides HBM latency
// under partition phases), then weight-table epilogue with one atomic/wave.
__device__ __forceinline__ void do_step(
        const unsigned int* __restrict__ pnt,
        const int* __restrict__ et_g, const int* __restrict__ es_g,
        const int* __restrict__ ed_g, const int* __restrict__ eb_g,
        const float* __restrict__ wt, float* __restrict__ out,
        unsigned int* lds, int tid, int lane,
        bool do_pre, long next_cb,
        int (&ET)[EPT], int (&SV)[EPT], int (&DV)[EPT], int (&EB)[EPT],
        int (&NET)[EPT], int (&NSV)[EPT], int (&NDV)[EPT], int (&NEB)[EPT]) {
    int enc[EPT];

    #pragma unroll
    for (int p = 0; p < NPART; ++p) {
        // ---- cooperative fill of partition p (L2-resident source) ----
        {
            const v4i* src = reinterpret_cast<const v4i*>(pnt) + (size_t)p * (PART_WORDS / 4);
            v4i* dst = reinterpret_cast<v4i*>(lds);
            v4i t0 = src[0 * THREADS + tid];
            v4i t1 = src[1 * THREADS + tid];
            v4i t2 = src[2 * THREADS + tid];
            v4i t3 = src[3 * THREADS + tid];
            dst[0 * THREADS + tid] = t0;
            dst[1 * THREADS + tid] = t1;
            dst[2 * THREADS + tid] = t2;
            dst[3 * THREADS + tid] = t3;
        }
        BAR();
        // Issue next-chunk stream prefetch once, after the first fill has
        // taken its vmcnt drain -> prefetch survives partition phases p0..p3.
        if (p == 0 && do_pre)
            prefetch_chunk(et_g, es_g, ed_g, eb_g, next_cb, NET, NSV, NDV, NEB);
        // ---- gather: dummy-address predication (inactive lanes broadcast
        // word 0 -> ~4x less bank work than unconditional random reads) ----
        #pragma unroll
        for (int k = 0; k < EPT; ++k) {
            if (p == 0) enc[k] = ET[k] * 9;
            unsigned s = (unsigned)SV[k];
            bool is = (s >> PART_BITS) == (unsigned)p;
            unsigned ws = lds[is ? ((s & (PART_NODES - 1u)) >> 4) : 0u];
            if (is) enc[k] += (int)((ws >> ((s & 15u) << 1)) & 3u) * 3;
            unsigned d = (unsigned)DV[k];
            bool id_ = (d >> PART_BITS) == (unsigned)p;
            unsigned wd = lds[id_ ? ((d & (PART_NODES - 1u)) >> 4) : 0u];
            if (id_) enc[k] += (int)((wd >> ((d & 15u) << 1)) & 3u);
        }
        BAR();
    }

    // ---- weight table into LDS head (nt table is dead for this chunk) ----
    for (int i = tid; i < TBL; i += THREADS) reinterpret_cast<float*>(lds)[i] = wt[i];
    BAR();

    // ---- epilogue: per-graph segmented sum ----
    {
        const float* lw = reinterpret_cast<const float*>(lds);
        int b0 = __shfl(EB[0], 0);        // first edge of wave window
        int bL = __shfl(EB[EPT - 1], 63); // last edge of wave window
        if (b0 == bL) {                   // sorted => whole window one graph
            float ssum = 0.0f;
            #pragma unroll
            for (int k = 0; k < EPT; ++k) ssum += lw[enc[k]];
            #pragma unroll
            for (int off = 32; off >= 1; off >>= 1)
                ssum += __shfl_down(ssum, off);
            if (lane == 0) atomicAdd(&out[b0], ssum);
        } else {
            // equality-merge of consecutive k's (always correct: merging on
            // equal batch ids needs no contiguity)
            float acc = 0.0f; int cur = -1;
            #pragma unroll
            for (int k = 0; k < EPT; ++k) {
                int bb = EB[k];
                float v = lw[enc[k]];
                if (bb != cur) {
                    if (cur >= 0) atomicAdd(&out[cur], acc);
                    cur = bb; acc = 0.0f;
                }
                acc += v;
            }
            if (cur >= 0) atomicAdd(&out[cur], acc);
        }
    }
    BAR();   // lw reads done before next chunk's fill overwrites LDS
}

__launch_bounds__(THREADS)
__global__ void edge_score_pipe(const unsigned int* __restrict__ pnt,
                                const int* __restrict__ et_g,
                                const int* __restrict__ es_g,
                                const int* __restrict__ ed_g,
                                const int* __restrict__ eb_g,
                                const float* __restrict__ wt,
                                float* __restrict__ out,
                                int nchunk) {
    __shared__ unsigned int lds[PART_WORDS];   // 64 KB
    const int tid  = threadIdx.x;
    const int lane = tid & 63;
    const int wid  = tid >> 6;

    const long blk_base = (long)blockIdx.x * ((long)nchunk * CHUNK);
    const long cb0      = blk_base + (long)wid * (64 * EPT) + (long)lane * 4;

    int etA[EPT], svA[EPT], dvA[EPT], ebA[EPT];
    int etB[EPT], svB[EPT], dvB[EPT], ebB[EPT];

    prefetch_chunk(et_g, es_g, ed_g, eb_g, cb0, etA, svA, dvA, ebA);

    for (int c = 0; c < nchunk; c += 2) {
        do_step(pnt, et_g, es_g, ed_g, eb_g, wt, out, lds, tid, lane,
                (c + 1) < nchunk, cb0 + (long)(c + 1) * CHUNK,
                etA, svA, dvA, ebA, etB, svB, dvB, ebB);
        if (c + 1 < nchunk)
            do_step(pnt, et_g, es_g, ed_g, eb_g, wt, out, lds, tid, lane,
                    (c + 2) < nchunk, cb0 + (long)(c + 2) * CHUNK,
                    etB, svB, dvB, ebB, etA, svA, dvA, ebA);
    }
}

// Per-edge fallback / tail kernel (direct gathers; correctness path).
__global__ void edge_score_simple(const int* __restrict__ nt,
                                  const int* __restrict__ et,
                                  const int* __restrict__ es,
                                  const int* __restrict__ ed,
                                  const int* __restrict__ eb,
                                  const float* __restrict__ w,
                                  float* __restrict__ out,
                                  long e0, long E) {
    long e = e0 + (long)blockIdx.x * blockDim.x + threadIdx.x;
    if (e >= E) return;
    int enc = et[e] * 9 + nt[es[e]] * 3 + nt[ed[e]];
    atomicAdd(&out[eb[e]], w[enc]);
}

extern "C" void kernel_launch(void* const* d_in, const int* in_sizes, int n_in,
                              void* d_out, int out_size, void* d_ws, size_t ws_size,
                              hipStream_t stream) {
    const int*   node_type  = (const int*)d_in[0];
    const int*   edge_type  = (const int*)d_in[1];
    const int*   edge_index = (const int*)d_in[2];   // [2, E]: src then dst
    const int*   edge_batch = (const int*)d_in[3];
    const float* w          = (const float*)d_in[4];
    float* out = (float*)d_out;

    long N = in_sizes[0];
    long E = in_sizes[1];
    const int* esrc = edge_index;
    const int* edst = edge_index + E;

    // d_out is poisoned once and never re-poisoned between replays; we
    // accumulate with atomics, so zero it at the start of every launch.
    zero_kernel<<<(out_size + 255) / 256, 256, 0, stream>>>(out, out_size);

    int  nwords  = (int)((N + 15) / 16);
    long nchunk  = E / ((long)NBLK * CHUNK);           // 4 for E = 2^24
    bool fast_ok = (ws_size >= (size_t)NPART * PART_WORDS * 4) &&
                   (N <= (long)NPART * PART_NODES) && (nchunk > 0);

    if (fast_ok) {
        unsigned int* pnt = (unsigned int*)d_ws;
        pack_nt_kernel<<<(nwords + 255) / 256, 256, 0, stream>>>(node_type, pnt, nwords, (int)N);

        edge_score_pipe<<<NBLK, THREADS, 0, stream>>>(
            pnt, edge_type, esrc, edst, edge_batch, w, out, (int)nchunk);

        long covered = (long)NBLK * nchunk * CHUNK;
        long rem     = E - covered;                    // 0 for this dataset
        if (rem > 0) {
            int tb = (int)((rem + 255) / 256);
            edge_score_simple<<<tb, 256, 0, stream>>>(
                node_type, edge_type, esrc, edst, edge_batch, w, out, covered, E);
        }
    } else {
        int tb = (int)((E + 255) / 256);
        edge_score_simple<<<tb, 256, 0, stream>>>(
            node_type, edge_type, esrc, edst, edge_batch, w, out, 0, E);
    }
}

// Round 7
// 155.224 us; speedup vs baseline: 1.5498x; 1.5498x over previous
//
#include <hip/hip_runtime.h>

typedef int v4i __attribute__((ext_vector_type(4)));

#define THREADS 1024
#define EPT 16                         // edges per thread per chunk
#define CHUNK (THREADS * EPT)          // 16384 edges
#define NBLK 256                       // persistent: 1 block per CU
#define PART_BITS 18
#define PART_NODES (1 << PART_BITS)    // 262144 nodes / partition
#define PART_WORDS (PART_NODES / 16)   // 16384 words = 64 KB
#define NPART 4
#define TBL 450                        // NUM_RELS * 9

// Barrier WITHOUT vmcnt drain: fill/stream loads stay in flight across it.
// lgkmcnt(0) makes ds_writes visible; sched_barrier pins (rule #18).
#define BAR() do {                                            \
    asm volatile("s_waitcnt lgkmcnt(0)" ::: "memory");        \
    __builtin_amdgcn_s_barrier();                             \
    __builtin_amdgcn_sched_barrier(0);                        \
} while (0)

__global__ void zero_kernel(float* __restrict__ out, int n) {
    int i = blockIdx.x * blockDim.x + threadIdx.x;
    if (i < n) out[i] = 0.0f;
}

// Pack node_type (0..2) into 2 bits/node: 16 nodes per uint32 (256 KB total).
__global__ void pack_nt_kernel(const int* __restrict__ nt,
                               unsigned int* __restrict__ packed,
                               int nwords, int N) {
    int i = blockIdx.x * blockDim.x + threadIdx.x;
    if (i >= nwords) return;
    unsigned int word = 0;
    int base = i * 16;
    if (base + 16 <= N) {
        #pragma unroll
        for (int j = 0; j < 4; ++j) {
            int4 v = *reinterpret_cast<const int4*>(nt + base + j * 4);
            word |= (unsigned)(v.x & 3) << (2 * (j * 4 + 0));
            word |= (unsigned)(v.y & 3) << (2 * (j * 4 + 1));
            word |= (unsigned)(v.z & 3) << (2 * (j * 4 + 2));
            word |= (unsigned)(v.w & 3) << (2 * (j * 4 + 3));
        }
    } else {
        for (int j = 0; base + j < N; ++j)
            word |= (unsigned)(nt[base + j] & 3) << (2 * j);
    }
    packed[i] = word;
}

// Double-buffered LDS partitions: fill(p+1) loads issue BEFORE gather(p),
// ds_write after -> L2 latency hides under gather compute. 128 KB LDS
// => 1 block/CU; __launch_bounds__(1024,4) => 128 VGPR cap (no spill at
// single stream buffer).
__launch_bounds__(THREADS, 4)
__global__ void edge_score_dbuf(const unsigned int* __restrict__ pnt,
                                const int* __restrict__ et_g,
                                const int* __restrict__ es_g,
                                const int* __restrict__ ed_g,
                                const int* __restrict__ eb_g,
                                const float* __restrict__ wt,
                                float* __restrict__ out,
                                int nchunk) {
    __shared__ __align__(16) unsigned int buf[2][PART_WORDS];   // 128 KB
    __shared__ float lw[TBL];                                    // 1.8 KB

    const int tid  = threadIdx.x;
    const int lane = tid & 63;
    const int wv   = tid >> 6;

    // Weight table: loaded once, lives in its own LDS region forever.
    if (tid < TBL) lw[tid] = wt[tid];

    const long blk0 = (long)blockIdx.x * ((long)nchunk * CHUNK);
    const v4i* fsrc = reinterpret_cast<const v4i*>(pnt);   // 4096 v4i/partition

    for (int c = 0; c < nchunk; ++c) {
        // Wave-contiguous window: wave wv owns 1024 edges, lane stride int4.
        const long cb = blk0 + (long)c * CHUNK + (long)wv * 1024 + (long)lane * 4;

        // ---- stream et/src/dst (eb deferred to epilogue; saves 16 VGPRs) ----
        v4i etv[4], svv[4], dvv[4];
        #pragma unroll
        for (int j = 0; j < 4; ++j) {
            etv[j] = __builtin_nontemporal_load(reinterpret_cast<const v4i*>(et_g + cb + j * 256));
            svv[j] = __builtin_nontemporal_load(reinterpret_cast<const v4i*>(es_g + cb + j * 256));
            dvv[j] = __builtin_nontemporal_load(reinterpret_cast<const v4i*>(ed_g + cb + j * 256));
        }
        // ---- fill loads for partition 0 ----
        v4i f[4];
        #pragma unroll
        for (int i = 0; i < 4; ++i) f[i] = fsrc[i * THREADS + tid];

        // unpack streams (compiler inserts counted vmcnt before first use)
        int sv[EPT], dv[EPT], enc[EPT];
        #pragma unroll
        for (int j = 0; j < 4; ++j) {
            #pragma unroll
            for (int q = 0; q < 4; ++q) {
                enc[j * 4 + q] = etv[j][q] * 9;
                sv[j * 4 + q]  = svv[j][q];
                dv[j * 4 + q]  = dvv[j][q];
            }
        }
        // ds_write fill p0 -> buf[0]
        {
            v4i* dst = reinterpret_cast<v4i*>(buf[0]);
            #pragma unroll
            for (int i = 0; i < 4; ++i) dst[i * THREADS + tid] = f[i];
        }
        BAR();   // buf[0] visible blockwide (also covers lw on c==0)

        #pragma unroll
        for (int p = 0; p < NPART; ++p) {
            // Issue fill loads for p+1 NOW -> latency hides under gather(p).
            if (p + 1 < NPART) {
                #pragma unroll
                for (int i = 0; i < 4; ++i)
                    f[i] = fsrc[(size_t)(p + 1) * (PART_WORDS / 4) + i * THREADS + tid];
            }
            // ---- gather partition p (predicated: inactive lanes read word 0,
            // a broadcast -> cheap). Grouped reads for ILP. ----
            const unsigned int* B = buf[p & 1];
            #pragma unroll
            for (int g = 0; g < 2; ++g) {
                unsigned wsv[8], wdv[8];
                #pragma unroll
                for (int k = 0; k < 8; ++k) {
                    unsigned s = (unsigned)sv[g * 8 + k];
                    wsv[k] = B[((s >> PART_BITS) == (unsigned)p) ? ((s & (PART_NODES - 1u)) >> 4) : 0u];
                    unsigned d = (unsigned)dv[g * 8 + k];
                    wdv[k] = B[((d >> PART_BITS) == (unsigned)p) ? ((d & (PART_NODES - 1u)) >> 4) : 0u];
                }
                #pragma unroll
                for (int k = 0; k < 8; ++k) {
                    unsigned s = (unsigned)sv[g * 8 + k];
                    unsigned d = (unsigned)dv[g * 8 + k];
                    if ((s >> PART_BITS) == (unsigned)p)
                        enc[g * 8 + k] += (int)((wsv[k] >> ((s & 15u) << 1)) & 3u) * 3;
                    if ((d >> PART_BITS) == (unsigned)p)
                        enc[g * 8 + k] += (int)((wdv[k] >> ((d & 15u) << 1)) & 3u);
                }
            }
            // ds_write fill p+1 to the other buffer (gather(p-1) readers of it
            // all passed the previous barrier).
            if (p + 1 < NPART) {
                v4i* dst = reinterpret_cast<v4i*>(buf[(p + 1) & 1]);
                #pragma unroll
                for (int i = 0; i < 4; ++i) dst[i * THREADS + tid] = f[i];
            }
            BAR();
        }

        // ---- epilogue: eb stream + LDS weight lookup + segmented atomics ----
        v4i ebv[4];
        #pragma unroll
        for (int j = 0; j < 4; ++j)
            ebv[j] = __builtin_nontemporal_load(reinterpret_cast<const v4i*>(eb_g + cb + j * 256));

        float val[EPT];
        #pragma unroll
        for (int k = 0; k < EPT; ++k) val[k] = lw[enc[k]];

        int wb0 = __shfl(ebv[0][0], 0);    // first edge of wave window
        int wbL = __shfl(ebv[3][3], 63);   // last edge of wave window
        if (wb0 == wbL) {                  // sorted => whole window one graph
            float s = 0.0f;
            #pragma unroll
            for (int k = 0; k < EPT; ++k) s += val[k];
            #pragma unroll
            for (int off = 32; off >= 1; off >>= 1)
                s += __shfl_down(s, off);
            if (lane == 0) atomicAdd(&out[wb0], s);
        } else {
            // equality-merge (correct regardless of per-thread contiguity)
            float acc = 0.0f; int cur = -1;
            #pragma unroll
            for (int k = 0; k < EPT; ++k) {
                int bb = ebv[k / 4][k % 4];
                if (bb != cur) {
                    if (cur >= 0) atomicAdd(&out[cur], acc);
                    cur = bb; acc = 0.0f;
                }
                acc += val[k];
            }
            if (cur >= 0) atomicAdd(&out[cur], acc);
        }
        // next chunk's first ds_write to buf[0] happens after the p=3 barrier
        // above; all buf reads completed before it. No extra barrier needed.
    }
}

// Per-edge fallback / tail kernel (direct gathers; correctness path).
__global__ void edge_score_simple(const int* __restrict__ nt,
                                  const int* __restrict__ et,
                                  const int* __restrict__ es,
                                  const int* __restrict__ ed,
                                  const int* __restrict__ eb,
                                  const float* __restrict__ w,
                                  float* __restrict__ out,
                                  long e0, long E) {
    long e = e0 + (long)blockIdx.x * blockDim.x + threadIdx.x;
    if (e >= E) return;
    int enc = et[e] * 9 + nt[es[e]] * 3 + nt[ed[e]];
    atomicAdd(&out[eb[e]], w[enc]);
}

extern "C" void kernel_launch(void* const* d_in, const int* in_sizes, int n_in,
                              void* d_out, int out_size, void* d_ws, size_t ws_size,
                              hipStream_t stream) {
    const int*   node_type  = (const int*)d_in[0];
    const int*   edge_type  = (const int*)d_in[1];
    const int*   edge_index = (const int*)d_in[2];   // [2, E]: src then dst
    const int*   edge_batch = (const int*)d_in[3];
    const float* w          = (const float*)d_in[4];
    float* out = (float*)d_out;

    long N = in_sizes[0];
    long E = in_sizes[1];
    const int* esrc = edge_index;
    const int* edst = edge_index + E;

    // d_out is poisoned once and never re-poisoned between replays; we
    // accumulate with atomics, so zero it at the start of every launch.
    zero_kernel<<<(out_size + 255) / 256, 256, 0, stream>>>(out, out_size);

    int  nwords = (int)((N + 15) / 16);
    long nchunk = E / ((long)NBLK * CHUNK);            // 4 for E = 2^24
    bool fast_ok = (ws_size >= (size_t)nwords * 4) &&
                   (N <= (long)NPART * PART_NODES) && (nchunk > 0);

    if (fast_ok) {
        unsigned int* pnt = (unsigned int*)d_ws;
        pack_nt_kernel<<<(nwords + 255) / 256, 256, 0, stream>>>(node_type, pnt, nwords, (int)N);

        edge_score_dbuf<<<NBLK, THREADS, 0, stream>>>(
            pnt, edge_type, esrc, edst, edge_batch, w, out, (int)nchunk);

        long covered = (long)NBLK * nchunk * CHUNK;
        long rem     = E - covered;                    // 0 for this dataset
        if (rem > 0) {
            int tb = (int)((rem + 255) / 256);
            edge_score_simple<<<tb, 256, 0, stream>>>(
                node_type, edge_type, esrc, edst, edge_batch, w, out, covered, E);
        }
    } else {
        int tb = (int)((E + 255) / 256);
        edge_score_simple<<<tb, 256, 0, stream>>>(
            node_type, edge_type, esrc, edst, edge_batch, w, out, 0, E);
    }
}

// Round 8
// 113.785 us; speedup vs baseline: 2.1142x; 1.3642x over previous
//
#include <hip/hip_runtime.h>

typedef int v4i __attribute__((ext_vector_type(4)));
typedef unsigned int u32;
typedef __attribute__((address_space(1))) const u32 gas_u32;
typedef __attribute__((address_space(3))) u32 las_u32;

#define THREADS 1024
#define NWAVES (THREADS / 64)
#define EPT 8                          // edges per thread per chunk
#define CHUNK (THREADS * EPT)          // 8192
#define NBLK 256                       // persistent: 1 block per CU
#define PART_BITS 19
#define PART_NODES (1 << PART_BITS)    // 524288 nodes per partition
#define PART_WORDS (PART_NODES / 16)   // 32768 u32 = 128 KB
#define TBL 450                        // NUM_RELS * 9
#define WAVE_WORDS (PART_WORDS / NWAVES)  // 2048 u32 = 8 KB per wave
#define DMA_PER_WAVE (WAVE_WORDS / 256)   // 8 x 1KB global_load_lds

// Barrier WITHOUT vmcnt drain (prefetch/DMA stay in flight); rule-18 fence.
#define BAR() do {                                            \
    asm volatile("s_waitcnt lgkmcnt(0)" ::: "memory");        \
    __builtin_amdgcn_s_barrier();                             \
    __builtin_amdgcn_sched_barrier(0);                        \
} while (0)

// Counted vmcnt wait (T4): never drain to 0 while prefetch is in flight.
#define WAITVM(n) do {                                        \
    asm volatile("s_waitcnt vmcnt(" #n ")" ::: "memory");     \
    __builtin_amdgcn_sched_barrier(0);                        \
} while (0)

__global__ void zero_kernel(float* __restrict__ out, int n) {
    int i = blockIdx.x * blockDim.x + threadIdx.x;
    if (i < n) out[i] = 0.0f;
}

// Pack node_type (0..2) into 2 bits/node: 16 nodes per uint32 (256 KB total).
__global__ void pack_nt_kernel(const int* __restrict__ nt,
                               unsigned int* __restrict__ packed,
                               int nwords, int N) {
    int i = blockIdx.x * blockDim.x + threadIdx.x;
    if (i >= nwords) return;
    unsigned int word = 0;
    int base = i * 16;
    if (base + 16 <= N) {
        #pragma unroll
        for (int j = 0; j < 4; ++j) {
            int4 v = *reinterpret_cast<const int4*>(nt + base + j * 4);
            word |= (unsigned)(v.x & 3) << (2 * (j * 4 + 0));
            word |= (unsigned)(v.y & 3) << (2 * (j * 4 + 1));
            word |= (unsigned)(v.z & 3) << (2 * (j * 4 + 2));
            word |= (unsigned)(v.w & 3) << (2 * (j * 4 + 3));
        }
    } else {
        for (int j = 0; base + j < N; ++j)
            word |= (unsigned)(nt[base + j] & 3) << (2 * j);
    }
    packed[i] = word;
}

// DMA one 128 KB partition into LDS: wave-uniform LDS base + per-lane global
// source (m97/m104 pattern). Zero VGPR cost, counted by vmcnt.
__device__ __forceinline__ void dma_fill(const u32* __restrict__ pnt,
                                         u32* lds_base, int p, int wv, int lane) {
    const u32* g = pnt + (size_t)p * PART_WORDS + wv * WAVE_WORDS + lane * 4;
    u32* l = lds_base + wv * WAVE_WORDS;
    #pragma unroll
    for (int i = 0; i < DMA_PER_WAVE; ++i)
        __builtin_amdgcn_global_load_lds((gas_u32*)(g + i * 256),
                                         (las_u32*)(l + i * 256), 16, 0, 0);
}

// Persistent kernel: per chunk (8192 edges) two phases {DMA fill 128 KB
// partition -> counted-vmcnt -> barrier -> predicated LDS gather}. Next-chunk
// streams issued in phase B (consumed next phase A: ~6 us slack hides HBM);
// eb issued in phase A (consumed at epilogue). Live regs ~56 < 64 cap.
__launch_bounds__(THREADS)
__global__ void edge_score_k(const u32* __restrict__ pnt,
                             const int* __restrict__ et_g,
                             const int* __restrict__ es_g,
                             const int* __restrict__ ed_g,
                             const int* __restrict__ eb_g,
                             const float* __restrict__ wt,
                             float* __restrict__ out,
                             int nchunk) {
    __shared__ __align__(16) u32 buf[PART_WORDS];   // 128 KB
    __shared__ float lw[TBL];                        // 1.8 KB, never overwritten

    const int tid  = threadIdx.x;
    const int lane = tid & 63;
    const int wv   = tid >> 6;

    if (tid < TBL) lw[tid] = wt[tid];

    const long blk0 = (long)blockIdx.x * ((long)nchunk * CHUNK);
    const long lb   = (long)wv * (64 * EPT) + (long)lane * 4;

    // prologue: streams for chunk 0 (6 nontemporal dwordx4 loads)
    v4i etv[2], svv[2], dvv[2];
    #pragma unroll
    for (int j = 0; j < 2; ++j) {
        etv[j] = __builtin_nontemporal_load((const v4i*)(et_g + blk0 + lb + j * 256));
        svv[j] = __builtin_nontemporal_load((const v4i*)(es_g + blk0 + lb + j * 256));
        dvv[j] = __builtin_nontemporal_load((const v4i*)(ed_g + blk0 + lb + j * 256));
    }

    for (int c = 0; c < nchunk; ++c) {
        const long cb = blk0 + (long)c * CHUNK + lb;

        // ---------------- phase A ----------------
        BAR();                               // gather1(c-1) done blockwide
        dma_fill(pnt, buf, 0, wv, lane);     // 8 DMA -> buf
        v4i ebv0 = __builtin_nontemporal_load((const v4i*)(eb_g + cb));
        v4i ebv1 = __builtin_nontemporal_load((const v4i*)(eb_g + cb + 256));
        int sv[EPT], dv[EPT], enc[EPT];
        #pragma unroll
        for (int j = 0; j < 2; ++j)
            #pragma unroll
            for (int q = 0; q < 4; ++q) {
                enc[j * 4 + q] = etv[j][q] * 9;   // compiler-waited stream regs
                sv[j * 4 + q]  = svv[j][q];
                dv[j * 4 + q]  = dvv[j][q];
            }
        WAITVM(2);                           // fill0 landed; eb(2) still in flight
        BAR();                               // fill0 visible blockwide
        #pragma unroll
        for (int k = 0; k < EPT; ++k) {      // gather partition 0
            unsigned s = (unsigned)sv[k], d = (unsigned)dv[k];
            bool as = (s >> PART_BITS) == 0u;
            bool ad = (d >> PART_BITS) == 0u;
            u32 ws = buf[as ? ((s >> 4) & (PART_WORDS - 1u)) : 0u];
            u32 wd = buf[ad ? ((d >> 4) & (PART_WORDS - 1u)) : 0u];
            if (as) enc[k] += (int)((ws >> ((s & 15u) << 1)) & 3u) * 3;
            if (ad) enc[k] += (int)((wd >> ((d & 15u) << 1)) & 3u);
        }

        // ---------------- phase B ----------------
        BAR();                               // gather0 done blockwide
        dma_fill(pnt, buf, 1, wv, lane);     // 8 DMA -> buf
        {   // next-chunk streams (clamped on last chunk: keeps vmcnt uniform)
            long nb = (c + 1 < nchunk) ? (cb + CHUNK) : cb;
            #pragma unroll
            for (int j = 0; j < 2; ++j) {
                etv[j] = __builtin_nontemporal_load((const v4i*)(et_g + nb + j * 256));
                svv[j] = __builtin_nontemporal_load((const v4i*)(es_g + nb + j * 256));
                dvv[j] = __builtin_nontemporal_load((const v4i*)(ed_g + nb + j * 256));
            }
        }
        WAITVM(6);                           // fill1 landed; streams(6) in flight
        BAR();                               // fill1 visible blockwide
        #pragma unroll
        for (int k = 0; k < EPT; ++k) {      // gather partition 1
            unsigned s = (unsigned)sv[k], d = (unsigned)dv[k];
            bool as = (s >> PART_BITS) == 1u;
            bool ad = (d >> PART_BITS) == 1u;
            u32 ws = buf[as ? ((s >> 4) & (PART_WORDS - 1u)) : 0u];
            u32 wd = buf[ad ? ((d >> 4) & (PART_WORDS - 1u)) : 0u];
            if (as) enc[k] += (int)((ws >> ((s & 15u) << 1)) & 3u) * 3;
            if (ad) enc[k] += (int)((wd >> ((d & 15u) << 1)) & 3u);
        }

        // ---------------- epilogue ----------------
        float val[EPT];
        #pragma unroll
        for (int k = 0; k < EPT; ++k) val[k] = lw[enc[k]];

        int wb0 = __shfl(ebv0[0], 0);        // first edge of wave window
        int wbL = __shfl(ebv1[3], 63);       // last edge of wave window
        if (wb0 == wbL) {                    // sorted => whole window one graph
            float ssum = 0.0f;
            #pragma unroll
            for (int k = 0; k < EPT; ++k) ssum += val[k];
            #pragma unroll
            for (int off = 32; off >= 1; off >>= 1)
                ssum += __shfl_down(ssum, off);
            if (lane == 0) atomicAdd(&out[wb0], ssum);
        } else {
            float acc = 0.0f; int cur = -1;
            #pragma unroll
            for (int k = 0; k < EPT; ++k) {
                int bb = (k < 4) ? ebv0[k] : ebv1[k - 4];   // static index
                if (bb != cur) {
                    if (cur >= 0) atomicAdd(&out[cur], acc);
                    cur = bb; acc = 0.0f;
                }
                acc += val[k];
            }
            if (cur >= 0) atomicAdd(&out[cur], acc);
        }
    }
}

// Per-edge fallback / tail kernel (direct gathers; correctness path).
__global__ void edge_score_simple(const int* __restrict__ nt,
                                  const int* __restrict__ et,
                                  const int* __restrict__ es,
                                  const int* __restrict__ ed,
                                  const int* __restrict__ eb,
                                  const float* __restrict__ w,
                                  float* __restrict__ out,
                                  long e0, long E) {
    long e = e0 + (long)blockIdx.x * blockDim.x + threadIdx.x;
    if (e >= E) return;
    int enc = et[e] * 9 + nt[es[e]] * 3 + nt[ed[e]];
    atomicAdd(&out[eb[e]], w[enc]);
}

extern "C" void kernel_launch(void* const* d_in, const int* in_sizes, int n_in,
                              void* d_out, int out_size, void* d_ws, size_t ws_size,
                              hipStream_t stream) {
    const int*   node_type  = (const int*)d_in[0];
    const int*   edge_type  = (const int*)d_in[1];
    const int*   edge_index = (const int*)d_in[2];   // [2, E]: src then dst
    const int*   edge_batch = (const int*)d_in[3];
    const float* w          = (const float*)d_in[4];
    float* out = (float*)d_out;

    long N = in_sizes[0];
    long E = in_sizes[1];
    const int* esrc = edge_index;
    const int* edst = edge_index + E;

    // d_out is poisoned once and never re-poisoned between replays; we
    // accumulate with atomics, so zero it at the start of every launch.
    zero_kernel<<<(out_size + 255) / 256, 256, 0, stream>>>(out, out_size);

    int  nwords = (int)((N + 15) / 16);
    long nchunk = E / ((long)NBLK * CHUNK);            // 8 for E = 2^24
    bool fast_ok = (ws_size >= (size_t)nwords * 4) &&
                   (N <= 2L * PART_NODES) && (nchunk > 0);

    if (fast_ok) {
        unsigned int* pnt = (unsigned int*)d_ws;
        pack_nt_kernel<<<(nwords + 255) / 256, 256, 0, stream>>>(node_type, pnt, nwords, (int)N);

        edge_score_k<<<NBLK, THREADS, 0, stream>>>(
            pnt, edge_type, esrc, edst, edge_batch, w, out, (int)nchunk);

        long covered = (long)NBLK * nchunk * CHUNK;
        long rem     = E - covered;                    // 0 for this dataset
        if (rem > 0) {
            int tb = (int)((rem + 255) / 256);
            edge_score_simple<<<tb, 256, 0, stream>>>(
                node_type, edge_type, esrc, edst, edge_batch, w, out, covered, E);
        }
    } else {
        int tb = (int)((E + 255) / 256);
        edge_score_simple<<<tb, 256, 0, stream>>>(
            node_type, edge_type, esrc, edst, edge_batch, w, out, 0, E);
    }
}